// Round 9
// baseline (772.791 us; speedup 1.0000x reference)
//
#include <hip/hip_runtime.h>

// ActorGCN collapsed-linear, fused via SOFTWARE grid barrier (2 dispatches).
// Identity: A(xW) = (Ax)W; BN stats of h = yW+b reduce to the 20x20
// covariance of y = A x. Hidden [N,1024] never materialized.
//
// Round 9: round-8's hipLaunchCooperativeKernel silently failed (out never
// written; return code unchecked). Replaced with a generation-counting
// software barrier: one agent-scope atomic arrival per block + threadfence
// on both sides (cross-XCD visibility of plain stores). Co-residency is
// guaranteed: __launch_bounds__(256,4) -> 4 blocks/CU x 256 CU = 1024 = grid;
// LDS 21.7KB x 4 = 87KB < 160KB/CU. Barrier state is in d_ws, re-zeroed by
// k_init every call -> idempotent across graph replays.
//
// Workspace (floats): deg N | dinv N | y 20N | stats 256 | params 64 | bar 64.

#define F 20
#define NSTAT 230
#define SROWS 256
#define NBLK 1024
#define BSZ 256

// init: deg=1 (self-loop), stats=0, params=0, barrier cnt/gen=0.
__global__ void k_init(float* __restrict__ deg, float* __restrict__ stats,
                       float* __restrict__ params, int* __restrict__ bar, int N) {
  int n = blockIdx.x * blockDim.x + threadIdx.x;
  if (n < N) deg[n] = 1.0f;
  if (n < 256) stats[n] = 0.f;
  if (n < 64) params[n] = 0.f;
  if (n < 2) bar[n * 32] = 0;  // cnt at bar[0], gen at bar[32] (128B apart)
}

__device__ __forceinline__ void gbar(int* cnt, int* gen, int nblk) {
  __syncthreads();
  if (threadIdx.x == 0) {
    __threadfence();  // release: push this block's stores toward coherent point
    int g = __hip_atomic_load(gen, __ATOMIC_RELAXED, __HIP_MEMORY_SCOPE_AGENT);
    if (__hip_atomic_fetch_add(cnt, 1, __ATOMIC_ACQ_REL, __HIP_MEMORY_SCOPE_AGENT) ==
        nblk - 1) {
      __hip_atomic_store(cnt, 0, __ATOMIC_RELAXED, __HIP_MEMORY_SCOPE_AGENT);
      __hip_atomic_fetch_add(gen, 1, __ATOMIC_RELEASE, __HIP_MEMORY_SCOPE_AGENT);
    } else {
      while (__hip_atomic_load(gen, __ATOMIC_ACQUIRE, __HIP_MEMORY_SCOPE_AGENT) == g) {
        __builtin_amdgcn_s_sleep(1);
      }
    }
    __threadfence();  // acquire: invalidate caches so we see others' stores
  }
  __syncthreads();
}

__global__ __launch_bounds__(BSZ, 4) void k_mega(
    const float* __restrict__ state, const float* __restrict__ edge_attr,
    const int* __restrict__ eidx,
    const float* __restrict__ W_gcn, const float* __restrict__ gamma,
    const float* __restrict__ beta, const float* __restrict__ W_lin,
    const float* __restrict__ b_lin,
    float* __restrict__ out,
    float* __restrict__ deg, float* __restrict__ dinv, float* __restrict__ y,
    float* __restrict__ stats, float* __restrict__ params, int* __restrict__ bar,
    int N, int Ns, int E, int H) {
  __shared__ float lds[SROWS * F];  // 20 KB (stats phase)
  __shared__ float Cu_s[210];
  __shared__ float ybar_s[F];
  __shared__ float P_s[64];

  int* cnt = bar;
  int* gen = bar + 32;
  const int* src = eidx;
  const int* dstp = eidx + E;
  const int gtid = blockIdx.x * blockDim.x + threadIdx.x;
  const int gsz = gridDim.x * blockDim.x;
  const int nblk = gridDim.x;
  const int t = threadIdx.x;
  const int lane = t & 63;

  // ---- P1: degree atomics ----
  for (int e = gtid; e < E; e += gsz) atomicAdd(&deg[dstp[e]], 1.0f);
  gbar(cnt, gen, nblk);

  // ---- P2: selfloop y = x/deg (float4) + dinv ----
  for (int t5 = gtid; t5 < N * 5; t5 += gsz) {
    int n = t5 / 5;
    int q = t5 - n * 5;
    float d = deg[n];
    const float* xrow = (n < Ns) ? (state + (size_t)n * F)
                                 : (edge_attr + (size_t)(n - Ns) * F);
    float4 v = *reinterpret_cast<const float4*>(xrow + q * 4);
    float inv = 1.0f / d;
    v.x *= inv; v.y *= inv; v.z *= inv; v.w *= inv;
    *reinterpret_cast<float4*>(y + (size_t)n * F + q * 4) = v;
    if (q == 0) dinv[n] = rsqrtf(d);
  }
  gbar(cnt, gen, nblk);

  // ---- P3: edge scatter, f-major scalar atomics (round-6 lesson:
  //      one-edge-per-lane float4 atomics thrash L2: 75.8MB WRITE, 2x time) ----
  {
    int tot = E * F;
    int sb = Ns * F;
    for (int i = gtid; i < tot; i += gsz) {
      int e = i / F;
      int f = i - e * F;
      int s = src[e];
      int d = dstp[e];
      float norm = dinv[s] * dinv[d];
      int xi = s * F + f;
      float x = (xi < sb) ? state[xi] : edge_attr[xi - sb];
      atomicAdd(&y[(size_t)d * F + f], norm * x);
    }
  }
  gbar(cnt, gen, nblk);

  // ---- P4: stats (20 col sums + 210 upper-tri moments), LDS-staged ----
  {
    int ci = 0, cj = 0;
    if (t >= F && t < NSTAT) {
      int k = t - F, i = 0;
      while (k >= F - i) { k -= F - i; i++; }
      ci = i; cj = i + k;
    }
    int nchunks = (N + SROWS - 1) / SROWS;
    long totalElems = (long)N * F;
    for (int b = blockIdx.x; b < nchunks; b += gridDim.x) {
      long e0 = (long)b * (SROWS * F);
      __syncthreads();
      for (int i4 = t; i4 < SROWS * F / 4; i4 += BSZ) {
        long gi = e0 + (long)i4 * 4;
        float4 v;
        if (gi + 3 < totalElems) v = *reinterpret_cast<const float4*>(y + gi);
        else { v.x = v.y = v.z = v.w = 0.f; }
        *reinterpret_cast<float4*>(lds + i4 * 4) = v;
      }
      __syncthreads();
      if (t < F) {
        float a0 = 0.f, a1 = 0.f, a2 = 0.f, a3 = 0.f;
        for (int r = 0; r < SROWS; r += 4) {
          a0 += lds[(r + 0) * F + t];
          a1 += lds[(r + 1) * F + t];
          a2 += lds[(r + 2) * F + t];
          a3 += lds[(r + 3) * F + t];
        }
        atomicAdd(&stats[t], (a0 + a1) + (a2 + a3));
      } else if (t < NSTAT) {
        float a0 = 0.f, a1 = 0.f, a2 = 0.f, a3 = 0.f;
        for (int r = 0; r < SROWS; r += 4) {
          a0 += lds[(r + 0) * F + ci] * lds[(r + 0) * F + cj];
          a1 += lds[(r + 1) * F + ci] * lds[(r + 1) * F + cj];
          a2 += lds[(r + 2) * F + ci] * lds[(r + 2) * F + cj];
          a3 += lds[(r + 3) * F + ci] * lds[(r + 3) * F + cj];
        }
        atomicAdd(&stats[t], (a0 + a1) + (a2 + a3));
      }
    }
  }
  gbar(cnt, gen, nblk);

  // ---- P5: finalize (Cu quadform per h, butterfly, atomicAdd params) ----
  {
    float invN = 1.0f / (float)N;
    int pb = (H + BSZ - 1) / BSZ;
    if (pb > (int)gridDim.x) pb = gridDim.x;
    if ((int)blockIdx.x < pb) {
      if (t < F) ybar_s[t] = stats[t] * invN;
      __syncthreads();
      if (t < 210) {
        int k = t, i = 0;
        while (k >= F - i) { k -= F - i; i++; }
        int j = i + k;
        float cv = stats[F + t] * invN - ybar_s[i] * ybar_s[j];
        Cu_s[t] = (i == j) ? cv : 2.0f * cv;  // fold symmetry
      }
      __syncthreads();
      for (int h = blockIdx.x * BSZ + t; h < H; h += pb * BSZ) {
        float w[F];
        #pragma unroll
        for (int f = 0; f < F; ++f) w[f] = W_gcn[f * H + h];  // coalesced
        float var = 0.f;
        int p = 0;
        #pragma unroll
        for (int i = 0; i < F; ++i) {
          float wi = w[i];
          #pragma unroll
          for (int j = i; j < F; ++j) { var += Cu_s[p] * (wi * w[j]); ++p; }
        }
        float sg = gamma[h] * rsqrtf(var + 1e-5f);
        float wl0 = W_lin[h * 2 + 0], wl1 = W_lin[h * 2 + 1];
        float s0 = sg * wl0, s1 = sg * wl1;
        #pragma unroll
        for (int f = 0; f < F; ++f) {
          float v0 = w[f] * s0, v1 = w[f] * s1;
          #pragma unroll
          for (int off = 32; off; off >>= 1) {
            v0 += __shfl_xor(v0, off);
            v1 += __shfl_xor(v1, off);
          }
          if (lane == 0) {
            atomicAdd(&params[2 * f + 0], v0);
            atomicAdd(&params[2 * f + 1], v1);
          }
        }
        float d0 = beta[h] * wl0, d1 = beta[h] * wl1;
        #pragma unroll
        for (int off = 32; off; off >>= 1) {
          d0 += __shfl_xor(d0, off);
          d1 += __shfl_xor(d1, off);
        }
        if (lane == 0) {
          atomicAdd(&params[40], d0);
          atomicAdd(&params[41], d1);
        }
      }
    }
    if (blockIdx.x == 0) {
      if (t < 2) atomicAdd(&params[40 + t], b_lin[t]);
      if (t >= 64 && t < 64 + F) params[42 + (t - 64)] = stats[t - 64] * invN;
    }
  }
  gbar(cnt, gen, nblk);

  // ---- P6: output logits=(y-ybar)@M+d, relu, 2-way softmax ----
  {
    if (t < 62) P_s[t] = params[t];
    __syncthreads();
    for (int n = gtid; n < N; n += gsz) {
      const float4* yr4 = reinterpret_cast<const float4*>(y + (size_t)n * F);
      float l0 = P_s[40], l1 = P_s[41];
      #pragma unroll
      for (int k = 0; k < 5; ++k) {
        float4 q = yr4[k];
        float vv[4] = {q.x, q.y, q.z, q.w};
        #pragma unroll
        for (int u = 0; u < 4; ++u) {
          int f = 4 * k + u;
          float dv = vv[u] - P_s[42 + f];
          l0 += dv * P_s[2 * f + 0];
          l1 += dv * P_s[2 * f + 1];
        }
      }
      l0 = fmaxf(l0, 0.f);
      l1 = fmaxf(l1, 0.f);
      float m = fmaxf(l0, l1);
      float e0 = __expf(l0 - m), e1 = __expf(l1 - m);
      float inv = 1.0f / (e0 + e1);
      float2 o2;
      o2.x = e0 * inv;
      o2.y = e1 * inv;
      reinterpret_cast<float2*>(out)[n] = o2;
    }
  }
}

extern "C" void kernel_launch(void* const* d_in, const int* in_sizes, int n_in,
                              void* d_out, int out_size, void* d_ws, size_t ws_size,
                              hipStream_t stream) {
  const float* state     = (const float*)d_in[0];
  const float* edge_attr = (const float*)d_in[1];
  const int*   eidx      = (const int*)d_in[2];
  const float* W_gcn     = (const float*)d_in[3];
  // d_in[4] = b_gcn: cancels inside batchnorm, unused.
  const float* gamma     = (const float*)d_in[5];
  const float* beta      = (const float*)d_in[6];
  const float* W_lin     = (const float*)d_in[7];
  const float* b_lin     = (const float*)d_in[8];
  float* out = (float*)d_out;

  int Ns = in_sizes[0] / F;
  int E  = in_sizes[2] / 2;
  int N  = Ns + in_sizes[1] / F;
  int H  = in_sizes[4];

  float* ws     = (float*)d_ws;
  float* deg    = ws;
  float* dinv   = ws + N;
  float* y      = ws + 2 * (size_t)N;
  float* stats  = y + (size_t)N * F;
  float* params = stats + 256;
  int*   bar    = (int*)(params + 64);

  k_init<<<(N + BSZ - 1) / BSZ, BSZ, 0, stream>>>(deg, stats, params, bar, N);
  k_mega<<<NBLK, BSZ, 0, stream>>>(state, edge_attr, eidx, W_gcn, gamma, beta,
                                   W_lin, b_lin, out, deg, dinv, y, stats,
                                   params, bar, N, Ns, E, H);
}

// Round 10
// 452.612 us; speedup vs baseline: 1.7074x; 1.7074x over previous
//
#include <hip/hip_runtime.h>

// ActorGCN collapsed-linear, fused megakernel v2 (2 dispatches).
// Identity: A(xW) = (Ax)W; BN stats of h = yW+b reduce to the 20x20
// covariance of y = A x. Hidden [N,1024] never materialized.
//
// Round 10: round-9's megakernel was correct but 780 us — ~144 us/barrier.
// Diagnosis: 1024 blocks spin-polling one line with agent-scope ACQUIRE
// loads (cache-invalidate per poll) at s_sleep(1). Fixes:
//  (a) RELAXED polls + single trailing __threadfence (acquire) on exit;
//  (b) hierarchical barrier: 32 groups x 32 blocks, <=32 pollers/line;
//  (c) s_sleep(8) poll period;
//  (d) barrier count 5 -> 4: finalize replicated per-block into LDS
//      (H=1024 quadform, ~4 us, W_gcn LLC-served), so P5->P6 is only
//      __syncthreads. Per-block finalize fits the 128-VGPR budget of
//      __launch_bounds__(256,4) (round-3's spill was the 64-VGPR cap of
//      1024-thread blocks).
//
// Workspace: deg N | dinv N | y 20N | stats 256 | bar 2112 ints.

#define F 20
#define NSTAT 230
#define SROWS 256
#define NBLK 1024
#define BSZ 256
#define NGRP 32   // groups
#define GRPB 32   // blocks per group

// init: deg=1 (self-loop), stats=0, barrier state=0.
__global__ void k_init(float* __restrict__ deg, float* __restrict__ stats,
                       int* __restrict__ bar, int N) {
  int n = blockIdx.x * blockDim.x + threadIdx.x;
  if (n < N) deg[n] = 1.0f;
  if (n < 256) stats[n] = 0.f;
  if (n < (2 + 2 * NGRP) * 32) bar[n] = 0;
}

// Hierarchical generation barrier. Layout (ints, 128B stride):
//   cnt0 = bar[0], gen0 = bar[32]
//   gcnt[g] = bar[(2+g)*32], ggen[g] = bar[(2+NGRP+g)*32]
__device__ __forceinline__ void gbar(int* __restrict__ bar) {
  __syncthreads();  // emits s_waitcnt vmcnt(0) -> all block stores in L2
  if (threadIdx.x == 0) {
    const int g = blockIdx.x >> 5;
    int* cnt0 = bar;
    int* gen0 = bar + 32;
    int* cntg = bar + (2 + g) * 32;
    int* geng = bar + (2 + NGRP + g) * 32;
    __threadfence();  // release: push this XCD's dirty L2 to coherent point
    int myg = __hip_atomic_load(geng, __ATOMIC_RELAXED, __HIP_MEMORY_SCOPE_AGENT);
    if (__hip_atomic_fetch_add(cntg, 1, __ATOMIC_ACQ_REL,
                               __HIP_MEMORY_SCOPE_AGENT) == GRPB - 1) {
      // group leader
      int g0 = __hip_atomic_load(gen0, __ATOMIC_RELAXED, __HIP_MEMORY_SCOPE_AGENT);
      if (__hip_atomic_fetch_add(cnt0, 1, __ATOMIC_ACQ_REL,
                                 __HIP_MEMORY_SCOPE_AGENT) == NGRP - 1) {
        __hip_atomic_store(cnt0, 0, __ATOMIC_RELAXED, __HIP_MEMORY_SCOPE_AGENT);
        __hip_atomic_fetch_add(gen0, 1, __ATOMIC_RELEASE, __HIP_MEMORY_SCOPE_AGENT);
      } else {
        while (__hip_atomic_load(gen0, __ATOMIC_RELAXED,
                                 __HIP_MEMORY_SCOPE_AGENT) == g0)
          __builtin_amdgcn_s_sleep(8);
      }
      __hip_atomic_store(cntg, 0, __ATOMIC_RELAXED, __HIP_MEMORY_SCOPE_AGENT);
      __hip_atomic_fetch_add(geng, 1, __ATOMIC_RELEASE, __HIP_MEMORY_SCOPE_AGENT);
    } else {
      while (__hip_atomic_load(geng, __ATOMIC_RELAXED,
                               __HIP_MEMORY_SCOPE_AGENT) == myg)
        __builtin_amdgcn_s_sleep(8);
    }
    __threadfence();  // acquire: invalidate local caches
  }
  __syncthreads();
}

__global__ __launch_bounds__(BSZ, 4) void k_mega(
    const float* __restrict__ state, const float* __restrict__ edge_attr,
    const int* __restrict__ eidx,
    const float* __restrict__ W_gcn, const float* __restrict__ gamma,
    const float* __restrict__ beta, const float* __restrict__ W_lin,
    const float* __restrict__ b_lin,
    float* __restrict__ out,
    float* __restrict__ deg, float* __restrict__ dinv, float* __restrict__ y,
    float* __restrict__ stats, int* __restrict__ bar,
    int N, int Ns, int E, int H) {
  __shared__ float lds[SROWS * F];  // 20 KB (stats phase)
  __shared__ float Cu_s[210];
  __shared__ float ybar_s[F];
  __shared__ float part[4][44];
  __shared__ float P_s[64];

  const int* src = eidx;
  const int* dstp = eidx + E;
  const int gtid = blockIdx.x * blockDim.x + threadIdx.x;
  const int gsz = gridDim.x * blockDim.x;
  const int t = threadIdx.x;
  const int lane = t & 63;
  const int wv = t >> 6;

  // ---- P1: degree atomics ----
  for (int e = gtid; e < E; e += gsz) atomicAdd(&deg[dstp[e]], 1.0f);
  gbar(bar);

  // ---- P2: selfloop y = x/deg (float4) + dinv ----
  for (int t5 = gtid; t5 < N * 5; t5 += gsz) {
    int n = t5 / 5;
    int q = t5 - n * 5;
    float d = deg[n];
    const float* xrow = (n < Ns) ? (state + (size_t)n * F)
                                 : (edge_attr + (size_t)(n - Ns) * F);
    float4 v = *reinterpret_cast<const float4*>(xrow + q * 4);
    float inv = 1.0f / d;
    v.x *= inv; v.y *= inv; v.z *= inv; v.w *= inv;
    *reinterpret_cast<float4*>(y + (size_t)n * F + q * 4) = v;
    if (q == 0) dinv[n] = rsqrtf(d);
  }
  gbar(bar);

  // ---- P3: edge scatter, f-major scalar atomics (round-6 lesson:
  //      one-edge-per-lane float4 atomics thrash L2) ----
  {
    int tot = E * F;
    int sb = Ns * F;
    for (int i = gtid; i < tot; i += gsz) {
      int e = i / F;
      int f = i - e * F;
      int s = src[e];
      int d = dstp[e];
      float norm = dinv[s] * dinv[d];
      int xi = s * F + f;
      float x = (xi < sb) ? state[xi] : edge_attr[xi - sb];
      atomicAdd(&y[(size_t)d * F + f], norm * x);
    }
  }
  gbar(bar);

  // ---- P4: stats (20 col sums + 210 upper-tri moments), LDS-staged ----
  {
    int ci = 0, cj = 0;
    if (t >= F && t < NSTAT) {
      int k = t - F, i = 0;
      while (k >= F - i) { k -= F - i; i++; }
      ci = i; cj = i + k;
    }
    int nchunks = (N + SROWS - 1) / SROWS;
    long totalElems = (long)N * F;
    for (int b = blockIdx.x; b < nchunks; b += gridDim.x) {
      long e0 = (long)b * (SROWS * F);
      __syncthreads();
      for (int i4 = t; i4 < SROWS * F / 4; i4 += BSZ) {
        long gi = e0 + (long)i4 * 4;
        float4 v;
        if (gi + 3 < totalElems) v = *reinterpret_cast<const float4*>(y + gi);
        else { v.x = v.y = v.z = v.w = 0.f; }
        *reinterpret_cast<float4*>(lds + i4 * 4) = v;
      }
      __syncthreads();
      if (t < F) {
        float a0 = 0.f, a1 = 0.f, a2 = 0.f, a3 = 0.f;
        for (int r = 0; r < SROWS; r += 4) {
          a0 += lds[(r + 0) * F + t];
          a1 += lds[(r + 1) * F + t];
          a2 += lds[(r + 2) * F + t];
          a3 += lds[(r + 3) * F + t];
        }
        atomicAdd(&stats[t], (a0 + a1) + (a2 + a3));
      } else if (t < NSTAT) {
        float a0 = 0.f, a1 = 0.f, a2 = 0.f, a3 = 0.f;
        for (int r = 0; r < SROWS; r += 4) {
          a0 += lds[(r + 0) * F + ci] * lds[(r + 0) * F + cj];
          a1 += lds[(r + 1) * F + ci] * lds[(r + 1) * F + cj];
          a2 += lds[(r + 2) * F + ci] * lds[(r + 2) * F + cj];
          a3 += lds[(r + 3) * F + ci] * lds[(r + 3) * F + cj];
        }
        atomicAdd(&stats[t], (a0 + a1) + (a2 + a3));
      }
    }
  }
  gbar(bar);

  // ---- P5: per-block finalize into LDS (no global barrier needed after) ----
  {
    float invN = 1.0f / (float)N;
    for (int i = t; i < 4 * 44; i += BSZ) ((float*)part)[i] = 0.f;
    if (t < F) ybar_s[t] = stats[t] * invN;
    __syncthreads();
    if (t < 210) {
      int k = t, i = 0;
      while (k >= F - i) { k -= F - i; i++; }
      int j = i + k;
      float cv = stats[F + t] * invN - ybar_s[i] * ybar_s[j];
      Cu_s[t] = (i == j) ? cv : 2.0f * cv;  // fold symmetry
    }
    __syncthreads();
    for (int h = t; h < H; h += BSZ) {
      float w[F];
      #pragma unroll
      for (int f = 0; f < F; ++f) w[f] = W_gcn[f * H + h];  // coalesced, LLC-hot
      float var = 0.f;
      int p = 0;
      #pragma unroll
      for (int i = 0; i < F; ++i) {
        float wi = w[i];
        #pragma unroll
        for (int j = i; j < F; ++j) { var += Cu_s[p] * (wi * w[j]); ++p; }
      }
      float sg = gamma[h] * rsqrtf(var + 1e-5f);
      float wl0 = W_lin[h * 2 + 0], wl1 = W_lin[h * 2 + 1];
      float s0 = sg * wl0, s1 = sg * wl1;
      #pragma unroll
      for (int f = 0; f < F; ++f) {
        float v0 = w[f] * s0, v1 = w[f] * s1;
        #pragma unroll
        for (int off = 32; off; off >>= 1) {
          v0 += __shfl_xor(v0, off);
          v1 += __shfl_xor(v1, off);
        }
        if (lane == 0) { part[wv][2 * f] += v0; part[wv][2 * f + 1] += v1; }
      }
      float d0 = beta[h] * wl0, d1 = beta[h] * wl1;
      #pragma unroll
      for (int off = 32; off; off >>= 1) {
        d0 += __shfl_xor(d0, off);
        d1 += __shfl_xor(d1, off);
      }
      if (lane == 0) { part[wv][40] += d0; part[wv][41] += d1; }
    }
    __syncthreads();
    if (t < 42) {
      float acc = 0.f;
      for (int w2 = 0; w2 < 4; ++w2) acc += part[w2][t];
      if (t >= 40) acc += b_lin[t - 40];
      P_s[t] = acc;
    } else if (t < 62) {
      P_s[t] = ybar_s[t - 42];
    }
    __syncthreads();
  }

  // ---- P6: output logits=(y-ybar)@M+d, relu, 2-way softmax ----
  {
    for (int n = gtid; n < N; n += gsz) {
      const float4* yr4 = reinterpret_cast<const float4*>(y + (size_t)n * F);
      float l0 = P_s[40], l1 = P_s[41];
      #pragma unroll
      for (int k = 0; k < 5; ++k) {
        float4 q = yr4[k];
        float vv[4] = {q.x, q.y, q.z, q.w};
        #pragma unroll
        for (int u = 0; u < 4; ++u) {
          int f = 4 * k + u;
          float dv = vv[u] - P_s[42 + f];
          l0 += dv * P_s[2 * f + 0];
          l1 += dv * P_s[2 * f + 1];
        }
      }
      l0 = fmaxf(l0, 0.f);
      l1 = fmaxf(l1, 0.f);
      float m = fmaxf(l0, l1);
      float e0 = __expf(l0 - m), e1 = __expf(l1 - m);
      float inv = 1.0f / (e0 + e1);
      float2 o2;
      o2.x = e0 * inv;
      o2.y = e1 * inv;
      reinterpret_cast<float2*>(out)[n] = o2;
    }
  }
}

extern "C" void kernel_launch(void* const* d_in, const int* in_sizes, int n_in,
                              void* d_out, int out_size, void* d_ws, size_t ws_size,
                              hipStream_t stream) {
  const float* state     = (const float*)d_in[0];
  const float* edge_attr = (const float*)d_in[1];
  const int*   eidx      = (const int*)d_in[2];
  const float* W_gcn     = (const float*)d_in[3];
  // d_in[4] = b_gcn: cancels inside batchnorm, unused.
  const float* gamma     = (const float*)d_in[5];
  const float* beta      = (const float*)d_in[6];
  const float* W_lin     = (const float*)d_in[7];
  const float* b_lin     = (const float*)d_in[8];
  float* out = (float*)d_out;

  int Ns = in_sizes[0] / F;
  int E  = in_sizes[2] / 2;
  int N  = Ns + in_sizes[1] / F;
  int H  = in_sizes[4];

  float* ws     = (float*)d_ws;
  float* deg    = ws;
  float* dinv   = ws + N;
  float* y      = ws + 2 * (size_t)N;
  float* stats  = y + (size_t)N * F;
  int*   bar    = (int*)(stats + 256);

  k_init<<<(N + BSZ - 1) / BSZ, BSZ, 0, stream>>>(deg, stats, bar, N);
  k_mega<<<NBLK, BSZ, 0, stream>>>(state, edge_attr, eidx, W_gcn, gamma, beta,
                                   W_lin, b_lin, out, deg, dinv, y, stats,
                                   bar, N, Ns, E, H);
}

// Round 11
// 136.928 us; speedup vs baseline: 5.6438x; 3.3055x over previous
//
#include <hip/hip_runtime.h>

// ActorGCN collapsed-linear, split pipeline, 5 dispatches.
// Identity: A(xW) = (Ax)W; BN stats of h = yW+b reduce to the 20x20
// covariance of y = A x. Hidden [N,1024] never materialized.
//
// Round 11: megakernel abandoned — round-9/10 proved grid-wide software
// barriers on 8-XCD MI355X cost more than kernel boundaries (fence-induced
// L2 writeback/invalidate inflated traffic 90->556 MB). Instead the split
// pipeline is restructured to 5 dispatches:
//   K1 init: y=0 (float4), deg=1, stats=0, done=0
//   K2 deg_acc: E dst atomics
//   K3 scatter: E*F f-major scalar atomics, norm = rsqrt(deg[s])*rsqrt(deg[d])
//      computed inline (dinv buffer + selfloop kernel eliminated)
//   K4 stats_fin: y_full = y_edge + x/deg (written back for K5), LDS stats,
//      done-counter; LAST block alone runs finalize -> params (no barrier)
//   K5 out: logits=(y-ybar)@M+d, relu, softmax
//
// Workspace (floats): deg N | y 20N | stats 256 | params 64 | done 1.

#define F 20
#define NSTAT 230
#define SROWS 256
#define BSZ 256

__global__ void k_init(float* __restrict__ deg, float4* __restrict__ y4,
                       float* __restrict__ stats, int* __restrict__ done, int N) {
  int i = blockIdx.x * blockDim.x + threadIdx.x;
  int tot5 = N * 5;  // y has N rows x 5 quads
  if (i < tot5) y4[i] = make_float4(0.f, 0.f, 0.f, 0.f);
  if (i < N) deg[i] = 1.0f;  // self-loop
  if (i < 256) stats[i] = 0.f;
  if (i == 0) *done = 0;
}

__global__ void k_deg_acc(const int* __restrict__ dst, float* __restrict__ deg, int E) {
  int e = blockIdx.x * blockDim.x + threadIdx.x;
  if (e < E) atomicAdd(&deg[dst[e]], 1.0f);
}

// thread per (edge, feature), f-major: each wave's 64 lanes span ~3 edges so
// each atomic instruction touches ~7 cache lines (round-6 lesson: one-edge-
// per-lane layouts thrash L2: 75.8 MB writes, 2x time).
__global__ void k_scatter(const int* __restrict__ src, const int* __restrict__ dst,
                          const float* __restrict__ deg,
                          const float* __restrict__ state,
                          const float* __restrict__ edge_attr,
                          float* __restrict__ y, int E, int Ns) {
  int tid = blockIdx.x * blockDim.x + threadIdx.x;
  if (tid >= E * F) return;
  int e = tid / F;
  int f = tid - e * F;
  int s = src[e];
  int d = dst[e];
  float norm = rsqrtf(deg[s]) * rsqrtf(deg[d]);  // inline, no dinv buffer
  int xi = s * F + f;
  int sb = Ns * F;
  float x = (xi < sb) ? state[xi] : edge_attr[xi - sb];
  atomicAdd(&y[(size_t)d * F + f], norm * x);
}

// Per 256-row block: y_full = y_edge + x/deg (written back), LDS-staged stats
// (20 col sums + 210 upper-tri moments), then done-counter; the LAST block
// alone computes params (Cu quadform per h, immediate butterfly into LDS).
__global__ __launch_bounds__(BSZ) void k_stats_fin(
    const float* __restrict__ state, const float* __restrict__ edge_attr,
    const float* __restrict__ deg, float* __restrict__ y,
    float* __restrict__ stats, int* __restrict__ done,
    const float* __restrict__ W_gcn, const float* __restrict__ gamma,
    const float* __restrict__ beta, const float* __restrict__ W_lin,
    const float* __restrict__ b_lin, float* __restrict__ params,
    int N, int Ns, int H, int nblk) {
  __shared__ float lds[SROWS * F];  // 20 KB
  __shared__ float Cu_s[210];
  __shared__ float ybar_s[F];
  __shared__ float part[4][44];
  __shared__ int amlast;

  int t = threadIdx.x;
  int lane = t & 63;
  int wv = t >> 6;

  // ---- combine self-term + stage into LDS, write y_full back ----
  long rowbase = (long)blockIdx.x * SROWS;
  for (int i4 = t; i4 < SROWS * 5; i4 += BSZ) {
    int rl = i4 / 5;            // local row
    int q = i4 - rl * 5;        // quad within row
    long row = rowbase + rl;
    float4 v = make_float4(0.f, 0.f, 0.f, 0.f);
    if (row < N) {
      long gi = row * F + q * 4;
      float4 ye = *reinterpret_cast<const float4*>(y + gi);
      const float* xrow = (row < (long)Ns) ? (state + row * F)
                                           : (edge_attr + (row - Ns) * F);
      float4 xv = *reinterpret_cast<const float4*>(xrow + q * 4);
      float di = 1.0f / deg[row];  // self-loop term x/deg
      v.x = ye.x + xv.x * di;
      v.y = ye.y + xv.y * di;
      v.z = ye.z + xv.z * di;
      v.w = ye.w + xv.w * di;
      *reinterpret_cast<float4*>(y + gi) = v;  // y_full for k_out
    }
    *reinterpret_cast<float4*>(lds + i4 * 4) = v;
  }
  __syncthreads();

  // ---- stats ----
  if (t < F) {
    float a0 = 0.f, a1 = 0.f, a2 = 0.f, a3 = 0.f;
    for (int r = 0; r < SROWS; r += 4) {
      a0 += lds[(r + 0) * F + t];
      a1 += lds[(r + 1) * F + t];
      a2 += lds[(r + 2) * F + t];
      a3 += lds[(r + 3) * F + t];
    }
    atomicAdd(&stats[t], (a0 + a1) + (a2 + a3));
  } else if (t < NSTAT) {
    int k = t - F, i = 0;
    while (k >= F - i) { k -= F - i; i++; }
    int ci = i, cj = i + k;
    float a0 = 0.f, a1 = 0.f, a2 = 0.f, a3 = 0.f;
    for (int r = 0; r < SROWS; r += 4) {
      a0 += lds[(r + 0) * F + ci] * lds[(r + 0) * F + cj];
      a1 += lds[(r + 1) * F + ci] * lds[(r + 1) * F + cj];
      a2 += lds[(r + 2) * F + ci] * lds[(r + 2) * F + cj];
      a3 += lds[(r + 3) * F + ci] * lds[(r + 3) * F + cj];
    }
    atomicAdd(&stats[t], (a0 + a1) + (a2 + a3));
  }
  __syncthreads();  // all this block's atomics issued & drained (vmcnt 0)

  // ---- done counter: last block proceeds alone ----
  if (t == 0) {
    __threadfence();
    int v = __hip_atomic_fetch_add(done, 1, __ATOMIC_ACQ_REL,
                                   __HIP_MEMORY_SCOPE_AGENT);
    amlast = (v == nblk - 1) ? 1 : 0;
  }
  __syncthreads();
  if (!amlast) return;
  __threadfence();  // acquire: see all blocks' stats atomics

  // ---- finalize (single block) ----
  float invN = 1.0f / (float)N;
  for (int i = t; i < 4 * 44; i += BSZ) ((float*)part)[i] = 0.f;
  if (t < F)
    ybar_s[t] = __hip_atomic_load(&stats[t], __ATOMIC_RELAXED,
                                  __HIP_MEMORY_SCOPE_AGENT) * invN;
  __syncthreads();
  if (t < 210) {
    int k = t, i = 0;
    while (k >= F - i) { k -= F - i; i++; }
    int j = i + k;
    float sv = __hip_atomic_load(&stats[F + t], __ATOMIC_RELAXED,
                                 __HIP_MEMORY_SCOPE_AGENT);
    float cv = sv * invN - ybar_s[i] * ybar_s[j];
    Cu_s[t] = (i == j) ? cv : 2.0f * cv;  // fold symmetry
  }
  __syncthreads();
  for (int h = t; h < H; h += BSZ) {
    float w[F];
    #pragma unroll
    for (int f = 0; f < F; ++f) w[f] = W_gcn[f * H + h];  // coalesced
    float var = 0.f;
    int p = 0;
    #pragma unroll
    for (int i = 0; i < F; ++i) {
      float wi = w[i];
      #pragma unroll
      for (int j = i; j < F; ++j) { var += Cu_s[p] * (wi * w[j]); ++p; }
    }
    float sg = gamma[h] * rsqrtf(var + 1e-5f);
    float wl0 = W_lin[h * 2 + 0], wl1 = W_lin[h * 2 + 1];
    float s0 = sg * wl0, s1 = sg * wl1;
    #pragma unroll
    for (int f = 0; f < F; ++f) {
      float v0 = w[f] * s0, v1 = w[f] * s1;
      #pragma unroll
      for (int off = 32; off; off >>= 1) {
        v0 += __shfl_xor(v0, off);
        v1 += __shfl_xor(v1, off);
      }
      if (lane == 0) { part[wv][2 * f] += v0; part[wv][2 * f + 1] += v1; }
    }
    float d0 = beta[h] * wl0, d1 = beta[h] * wl1;
    #pragma unroll
    for (int off = 32; off; off >>= 1) {
      d0 += __shfl_xor(d0, off);
      d1 += __shfl_xor(d1, off);
    }
    if (lane == 0) { part[wv][40] += d0; part[wv][41] += d1; }
  }
  __syncthreads();
  if (t < 42) {
    float acc = 0.f;
    for (int w2 = 0; w2 < 4; ++w2) acc += part[w2][t];
    if (t >= 40) acc += b_lin[t - 40];
    params[t] = acc;
  } else if (t < 62) {
    params[t] = ybar_s[t - 42];
  }
}

// thread per node: logits = (y[n]-ybar) @ M + d; relu; 2-way softmax.
__global__ void k_out(const float* __restrict__ y,
                      const float* __restrict__ params,
                      float* __restrict__ out, int N) {
  __shared__ float P[64];
  if (threadIdx.x < 62) P[threadIdx.x] = params[threadIdx.x];
  __syncthreads();
  int n = blockIdx.x * blockDim.x + threadIdx.x;
  if (n >= N) return;
  const float4* yr4 = reinterpret_cast<const float4*>(y + (size_t)n * F);
  float l0 = P[40], l1 = P[41];
  #pragma unroll
  for (int k = 0; k < 5; ++k) {
    float4 q = yr4[k];
    float vv[4] = {q.x, q.y, q.z, q.w};
    #pragma unroll
    for (int u = 0; u < 4; ++u) {
      int f = 4 * k + u;
      float dv = vv[u] - P[42 + f];
      l0 += dv * P[2 * f + 0];
      l1 += dv * P[2 * f + 1];
    }
  }
  l0 = fmaxf(l0, 0.f);
  l1 = fmaxf(l1, 0.f);
  float m = fmaxf(l0, l1);
  float e0 = __expf(l0 - m), e1 = __expf(l1 - m);
  float inv = 1.0f / (e0 + e1);
  float2 o2;
  o2.x = e0 * inv;
  o2.y = e1 * inv;
  reinterpret_cast<float2*>(out)[n] = o2;
}

extern "C" void kernel_launch(void* const* d_in, const int* in_sizes, int n_in,
                              void* d_out, int out_size, void* d_ws, size_t ws_size,
                              hipStream_t stream) {
  const float* state     = (const float*)d_in[0];
  const float* edge_attr = (const float*)d_in[1];
  const int*   eidx      = (const int*)d_in[2];
  const float* W_gcn     = (const float*)d_in[3];
  // d_in[4] = b_gcn: cancels inside batchnorm, unused.
  const float* gamma     = (const float*)d_in[5];
  const float* beta      = (const float*)d_in[6];
  const float* W_lin     = (const float*)d_in[7];
  const float* b_lin     = (const float*)d_in[8];
  float* out = (float*)d_out;

  int Ns = in_sizes[0] / F;
  int E  = in_sizes[2] / 2;
  int N  = Ns + in_sizes[1] / F;
  int H  = in_sizes[4];

  const int* src = eidx;
  const int* dst = eidx + E;

  float* ws     = (float*)d_ws;
  float* deg    = ws;
  float* y      = ws + N;
  float* stats  = y + (size_t)N * F;
  float* params = stats + 256;
  int*   done   = (int*)(params + 64);

  int nblk = (N + SROWS - 1) / SROWS;

  k_init<<<(N * 5 + BSZ - 1) / BSZ, BSZ, 0, stream>>>(
      deg, (float4*)y, stats, done, N);
  k_deg_acc<<<(E + BSZ - 1) / BSZ, BSZ, 0, stream>>>(dst, deg, E);
  k_scatter<<<(E * F + BSZ - 1) / BSZ, BSZ, 0, stream>>>(
      src, dst, deg, state, edge_attr, y, E, Ns);
  k_stats_fin<<<nblk, BSZ, 0, stream>>>(
      state, edge_attr, deg, y, stats, done,
      W_gcn, gamma, beta, W_lin, b_lin, params, N, Ns, H, nblk);
  k_out<<<(N + BSZ - 1) / BSZ, BSZ, 0, stream>>>(y, params, out, N);
}

// Round 12
// 104.832 us; speedup vs baseline: 7.3717x; 1.3062x over previous
//
#include <hip/hip_runtime.h>

// ActorGCN collapsed-linear, split pipeline, 6 dispatches.
// Identity: A(xW) = (Ax)W; BN stats of h = yW+b reduce to the 20x20
// covariance of y = A x. Hidden [N,1024] never materialized.
//
// Round 12: round-11 fused finalize into stats -> VGPR 136 (was 20) ->
// 3 waves/SIMD instead of 8 -> latency-bound LDS loop lost its TLP
// (88 us, occ 5.6%). Finalize is split back out (register pressure is
// per-kernel max!); stats keeps the profitable fusions from round 11:
//   - selfloop kernel eliminated: self-term x/deg folded into stats staging,
//     y_full written back for k_out (saves a 16.6MB read+write pass)
//   - dinv buffer eliminated: scatter computes rsqrt(deg) inline
// Pipeline:
//   K1 init: y=0 (float4), deg=1, stats=0
//   K2 deg_acc: E dst atomics
//   K3 scatter: E*F f-major scalar atomics (round-6: one-edge-per-lane
//      float4 atomics thrash L2 -> keep f-major scalar)
//   K4 stats: y_full = y_edge + x/deg -> writeback + LDS moments (reg-light)
//   K5 finalize: 1 block, reg-heavy quadform (round-4 proven form)
//   K6 out: logits=(y-ybar)@M+d, relu, softmax
//
// Workspace (floats): deg N | y 20N | stats 256 | params 64.

#define F 20
#define NSTAT 230
#define SROWS 256
#define BSZ 256

__global__ void k_init(float* __restrict__ deg, float4* __restrict__ y4,
                       float* __restrict__ stats, int N) {
  int i = blockIdx.x * blockDim.x + threadIdx.x;
  if (i < N * 5) y4[i] = make_float4(0.f, 0.f, 0.f, 0.f);
  if (i < N) deg[i] = 1.0f;  // self-loop
  if (i < 256) stats[i] = 0.f;
}

__global__ void k_deg_acc(const int* __restrict__ dst, float* __restrict__ deg, int E) {
  int e = blockIdx.x * blockDim.x + threadIdx.x;
  if (e < E) atomicAdd(&deg[dst[e]], 1.0f);
}

// thread per (edge, feature), f-major: each wave's 64 lanes span ~3 edges so
// each atomic instruction touches ~7 cache lines.
__global__ void k_scatter(const int* __restrict__ src, const int* __restrict__ dst,
                          const float* __restrict__ deg,
                          const float* __restrict__ state,
                          const float* __restrict__ edge_attr,
                          float* __restrict__ y, int E, int Ns) {
  int tid = blockIdx.x * blockDim.x + threadIdx.x;
  if (tid >= E * F) return;
  int e = tid / F;
  int f = tid - e * F;
  int s = src[e];
  int d = dst[e];
  float norm = rsqrtf(deg[s]) * rsqrtf(deg[d]);  // inline, no dinv buffer
  int xi = s * F + f;
  int sb = Ns * F;
  float x = (xi < sb) ? state[xi] : edge_attr[xi - sb];
  atomicAdd(&y[(size_t)d * F + f], norm * x);
}

// Per 256-row block: y_full = y_edge + x/deg (written back for k_out),
// LDS-staged stats (20 col sums + 210 upper-tri moments), one atomicAdd
// per stat per block. Register-light: no finalize code in this kernel.
__global__ __launch_bounds__(BSZ) void k_stats(
    const float* __restrict__ state, const float* __restrict__ edge_attr,
    const float* __restrict__ deg, float* __restrict__ y,
    float* __restrict__ stats, int N, int Ns) {
  __shared__ float lds[SROWS * F];  // 20 KB
  int t = threadIdx.x;

  long rowbase = (long)blockIdx.x * SROWS;
  for (int i4 = t; i4 < SROWS * 5; i4 += BSZ) {
    int rl = i4 / 5;
    int q = i4 - rl * 5;
    long row = rowbase + rl;
    float4 v = make_float4(0.f, 0.f, 0.f, 0.f);
    if (row < N) {
      long gi = row * F + q * 4;
      float4 ye = *reinterpret_cast<const float4*>(y + gi);
      const float* xrow = (row < (long)Ns) ? (state + row * F)
                                           : (edge_attr + (row - Ns) * F);
      float4 xv = *reinterpret_cast<const float4*>(xrow + q * 4);
      float di = 1.0f / deg[row];  // self-loop term x/deg
      v.x = ye.x + xv.x * di;
      v.y = ye.y + xv.y * di;
      v.z = ye.z + xv.z * di;
      v.w = ye.w + xv.w * di;
      *reinterpret_cast<float4*>(y + gi) = v;  // y_full for k_out
    }
    *reinterpret_cast<float4*>(lds + i4 * 4) = v;
  }
  __syncthreads();

  if (t < F) {
    float a0 = 0.f, a1 = 0.f, a2 = 0.f, a3 = 0.f;
    for (int r = 0; r < SROWS; r += 4) {
      a0 += lds[(r + 0) * F + t];
      a1 += lds[(r + 1) * F + t];
      a2 += lds[(r + 2) * F + t];
      a3 += lds[(r + 3) * F + t];
    }
    atomicAdd(&stats[t], (a0 + a1) + (a2 + a3));
  } else if (t < NSTAT) {
    int k = t - F, i = 0;
    while (k >= F - i) { k -= F - i; i++; }
    int ci = i, cj = i + k;
    float a0 = 0.f, a1 = 0.f, a2 = 0.f, a3 = 0.f;
    for (int r = 0; r < SROWS; r += 4) {
      a0 += lds[(r + 0) * F + ci] * lds[(r + 0) * F + cj];
      a1 += lds[(r + 1) * F + ci] * lds[(r + 1) * F + cj];
      a2 += lds[(r + 2) * F + ci] * lds[(r + 2) * F + cj];
      a3 += lds[(r + 3) * F + ci] * lds[(r + 3) * F + cj];
    }
    atomicAdd(&stats[t], (a0 + a1) + (a2 + a3));
  }
}

// Single block, 256 threads, launch_bounds(256,1): 4 waves -> up to 512
// VGPR/thread; w[4][20] + m0[20] + m1[20] live in registers (round-4 proven).
__global__ __launch_bounds__(256, 1) void k_finalize(
    const float* __restrict__ stats,
    const float* __restrict__ W_gcn,
    const float* __restrict__ gamma,
    const float* __restrict__ beta,
    const float* __restrict__ W_lin,
    const float* __restrict__ b_lin,
    float* __restrict__ params,
    int N, int H) {
  __shared__ float Cu_s[210];
  __shared__ float ybar_s[F];
  __shared__ float part[4][44];
  int t = threadIdx.x;
  int lane = t & 63;
  int wv = t >> 6;
  float invN = 1.0f / (float)N;
  if (t < F) ybar_s[t] = stats[t] * invN;
  __syncthreads();
  if (t < 210) {
    int k = t, i = 0;
    while (k >= F - i) { k -= F - i; i++; }
    int j = i + k;
    float cv = stats[F + t] * invN - ybar_s[i] * ybar_s[j];
    Cu_s[t] = (i == j) ? cv : 2.0f * cv;  // fold symmetry factor
  }
  __syncthreads();

  float m0[F], m1[F];
  #pragma unroll
  for (int f = 0; f < F; ++f) { m0[f] = 0.f; m1[f] = 0.f; }
  float d0 = 0.f, d1 = 0.f;

  for (int hb = 0; hb < H; hb += 4 * 256) {
    float w[4][F];
    float var[4];
    int hh[4];
    bool act[4];
    #pragma unroll
    for (int c = 0; c < 4; ++c) {
      int h = hb + c * 256 + t;
      act[c] = (h < H);
      hh[c] = act[c] ? h : 0;
      var[c] = 0.f;
      #pragma unroll
      for (int f = 0; f < F; ++f) {
        float x = W_gcn[f * H + hh[c]];  // coalesced over t
        w[c][f] = act[c] ? x : 0.f;
      }
    }
    int p = 0;
    #pragma unroll
    for (int i = 0; i < F; ++i) {
      #pragma unroll
      for (int j = i; j < F; ++j) {
        float cu = Cu_s[p];  // uniform broadcast, reused 4x
        ++p;
        #pragma unroll
        for (int c = 0; c < 4; ++c) var[c] += cu * (w[c][i] * w[c][j]);
      }
    }
    #pragma unroll
    for (int c = 0; c < 4; ++c) {
      float sg = act[c] ? (gamma[hh[c]] * rsqrtf(var[c] + 1e-5f)) : 0.f;
      float wl0 = W_lin[hh[c] * 2 + 0], wl1 = W_lin[hh[c] * 2 + 1];
      float s0 = sg * wl0, s1 = sg * wl1;
      #pragma unroll
      for (int f = 0; f < F; ++f) { m0[f] += w[c][f] * s0; m1[f] += w[c][f] * s1; }
      float bt = act[c] ? beta[hh[c]] : 0.f;
      d0 += bt * wl0;
      d1 += bt * wl1;
    }
  }

  #pragma unroll
  for (int f = 0; f < F; ++f) {
    float v0 = m0[f], v1 = m1[f];
    #pragma unroll
    for (int off = 32; off; off >>= 1) {
      v0 += __shfl_xor(v0, off);
      v1 += __shfl_xor(v1, off);
    }
    if (lane == 0) { part[wv][2 * f] = v0; part[wv][2 * f + 1] = v1; }
  }
  #pragma unroll
  for (int off = 32; off; off >>= 1) {
    d0 += __shfl_xor(d0, off);
    d1 += __shfl_xor(d1, off);
  }
  if (lane == 0) { part[wv][40] = d0; part[wv][41] = d1; }
  __syncthreads();

  if (t < 42) {
    float acc = 0.f;
    for (int w2 = 0; w2 < 4; ++w2) acc += part[w2][t];
    if (t >= 40) acc += b_lin[t - 40];
    params[t] = acc;
  } else if (t < 62) {
    params[t] = ybar_s[t - 42];
  }
}

// thread per node: logits = (y[n]-ybar) @ M + d; relu; 2-way softmax.
__global__ void k_out(const float* __restrict__ y,
                      const float* __restrict__ params,
                      float* __restrict__ out, int N) {
  __shared__ float P[64];
  if (threadIdx.x < 62) P[threadIdx.x] = params[threadIdx.x];
  __syncthreads();
  int n = blockIdx.x * blockDim.x + threadIdx.x;
  if (n >= N) return;
  const float4* yr4 = reinterpret_cast<const float4*>(y + (size_t)n * F);
  float l0 = P[40], l1 = P[41];
  #pragma unroll
  for (int k = 0; k < 5; ++k) {
    float4 q = yr4[k];
    float vv[4] = {q.x, q.y, q.z, q.w};
    #pragma unroll
    for (int u = 0; u < 4; ++u) {
      int f = 4 * k + u;
      float dv = vv[u] - P[42 + f];
      l0 += dv * P[2 * f + 0];
      l1 += dv * P[2 * f + 1];
    }
  }
  l0 = fmaxf(l0, 0.f);
  l1 = fmaxf(l1, 0.f);
  float m = fmaxf(l0, l1);
  float e0 = __expf(l0 - m), e1 = __expf(l1 - m);
  float inv = 1.0f / (e0 + e1);
  float2 o2;
  o2.x = e0 * inv;
  o2.y = e1 * inv;
  reinterpret_cast<float2*>(out)[n] = o2;
}

extern "C" void kernel_launch(void* const* d_in, const int* in_sizes, int n_in,
                              void* d_out, int out_size, void* d_ws, size_t ws_size,
                              hipStream_t stream) {
  const float* state     = (const float*)d_in[0];
  const float* edge_attr = (const float*)d_in[1];
  const int*   eidx      = (const int*)d_in[2];
  const float* W_gcn     = (const float*)d_in[3];
  // d_in[4] = b_gcn: cancels inside batchnorm, unused.
  const float* gamma     = (const float*)d_in[5];
  const float* beta      = (const float*)d_in[6];
  const float* W_lin     = (const float*)d_in[7];
  const float* b_lin     = (const float*)d_in[8];
  float* out = (float*)d_out;

  int Ns = in_sizes[0] / F;
  int E  = in_sizes[2] / 2;
  int N  = Ns + in_sizes[1] / F;
  int H  = in_sizes[4];

  const int* src = eidx;
  const int* dst = eidx + E;

  float* ws     = (float*)d_ws;
  float* deg    = ws;
  float* y      = ws + N;
  float* stats  = y + (size_t)N * F;
  float* params = stats + 256;

  int nblk = (N + SROWS - 1) / SROWS;

  k_init<<<(N * 5 + BSZ - 1) / BSZ, BSZ, 0, stream>>>(deg, (float4*)y, stats, N);
  k_deg_acc<<<(E + BSZ - 1) / BSZ, BSZ, 0, stream>>>(dst, deg, E);
  k_scatter<<<(E * F + BSZ - 1) / BSZ, BSZ, 0, stream>>>(
      src, dst, deg, state, edge_attr, y, E, Ns);
  k_stats<<<nblk, BSZ, 0, stream>>>(state, edge_attr, deg, y, stats, N, Ns);
  k_finalize<<<1, 256, 0, stream>>>(stats, W_gcn, gamma, beta, W_lin, b_lin,
                                    params, N, H);
  k_out<<<(N + BSZ - 1) / BSZ, BSZ, 0, stream>>>(y, params, out, N);
}